// Round 7
// baseline (3064.236 us; speedup 1.0000x reference)
//
#include <hip/hip_runtime.h>

// NeuralODE, ALL-F32 I/O.
// GRU encoder: fused [x|h] @ [Wih|Whh]^T via f16 MFMA (hi/lo).
// h2o MLP: f32 VALU. o2d MLP: f16 MFMA hi/lo.
// Tsit5 x255: 256-thread WG (4 waves, 1/SIMD) to halve broadcast-LDS
// redundancy. Per wave: 64 outputs (4 n-tiles) of L0/L1/L2; L3 K-chunk =
// the wave's own 64 x2 components (register->per-wave LDS roundtrip, no
// barrier). 3 barriers/feval: [L1][L2+L3part][reduce+update+L0].
// Weights in VGPRs (~390): W1/W2 hi-only, W0/Wout hi+lo.
// ys workspace: u32-packed f16 (hi | lo<<16) = 4 MB.

typedef unsigned short u16;
typedef unsigned int u32;
typedef _Float16 f16;
typedef __attribute__((ext_vector_type(8))) _Float16 f16x8;
typedef __attribute__((ext_vector_type(4))) float f32x4;

#define MFMA16(A, B, C) __builtin_amdgcn_mfma_f32_16x16x32_f16((A), (B), (C), 0, 0, 0)

__device__ __forceinline__ u16 f16bits(f16 h) { union { f16 f; u16 u; } c; c.f = h; return c.u; }
__device__ __forceinline__ f16 bitsf16(u16 u) { union { f16 f; u16 u; } c; c.u = u; return c.f; }
__device__ __forceinline__ void split(float v, f16& hi, f16& lo) {
    hi = (f16)v;
    lo = (f16)(v - (float)hi);
}
__device__ __forceinline__ u32 packf16(float v) {
    f16 hi, lo;
    split(v, hi, lo);
    return (u32)f16bits(hi) | ((u32)f16bits(lo) << 16);
}
__device__ __forceinline__ float fsig(float x) { return 1.0f / (1.0f + __expf(-x)); }
__device__ __forceinline__ float ftanh(float x) {
    float e = __expf(2.0f * x);
    return 1.0f - 2.0f / (e + 1.0f);
}

// Tsit5 tableau: rows 0..4 = stage-argument coefficients, row 5 = final update.
constexpr float cAc[6][6] = {
    {0.161f, 0.f, 0.f, 0.f, 0.f, 0.f},
    {-0.008480655492356989f, 0.335480655492357f, 0.f, 0.f, 0.f, 0.f},
    {2.8971530571054935f, -6.359448489975075f, 4.3622954328695815f, 0.f, 0.f, 0.f},
    {5.325864828439257f, -11.748883564062828f, 7.4955393428898365f, -0.09249506636175525f, 0.f, 0.f},
    {5.86145544294642f, -12.92096931784711f, 8.159367898576159f, -0.071584973281401f, -0.028269050394068383f, 0.f},
    {0.09646076681806523f, 0.01f, 0.4798896504144996f, 1.379008574103742f, -3.290069515436081f, 2.324710524099774f}};

// =====================================================================
// Kernel 1: GRU (MFMA f16) + h2o MLP (f32 VALU). One WG / batch row.
// =====================================================================
__global__ __launch_bounds__(256, 1) void gru_h2o_kernel(
    const float* __restrict__ yi,   // [256,256,16]
    const float* __restrict__ wih,  // [384,16]
    const float* __restrict__ whh,  // [384,128]
    const float* __restrict__ gb,   // [384]
    const float* __restrict__ gbn,  // [128]
    const float* __restrict__ hW1, const float* __restrict__ hb1,  // [256,128],[256]
    const float* __restrict__ hW2, const float* __restrict__ hb2,  // [256,256],[256]
    const float* __restrict__ hW3, const float* __restrict__ hb3,  // [32,256],[32]
    u32* __restrict__ ys)  // [256,256,32] packed f16 hi|lo; writes ys[0]
{
    const int b = blockIdx.x;
    const int tid = threadIdx.x;
    const int wave = tid >> 6;
    const int lane = tid & 63;
    const int quad = lane >> 4;
    const int col = lane & 15;

    // A layout rows: 0=(x|h)hi 1=(x|h)lo 2=(x|0)hi 3=(x|0)lo ; K=160 (144+pad)
    __shared__ alignas(16) f16 s_a[4][160];
    __shared__ float s_sum[384];
    __shared__ float s_icc[384];
    __shared__ float s_h[128];
    __shared__ float s_t[256];

    for (int i = tid; i < 640; i += 256) ((f16*)s_a)[i] = (f16)0.0f;

    const f32x4 ZC = {0.f, 0.f, 0.f, 0.f};

    // ---- combined-weight fragments: W[n][k] = wih|whh|0, hi+lo f16 ----
    f16x8 wf[6][5][2];
#pragma unroll
    for (int tt = 0; tt < 6; ++tt) {
        const int n = (wave * 6 + tt) * 16 + col;
#pragma unroll
        for (int kk = 0; kk < 5; ++kk) {
            const int k0 = kk * 32 + quad * 8;
            float w8[8];
            if (k0 < 16) {
#pragma unroll
                for (int j = 0; j < 8; ++j) w8[j] = wih[n * 16 + k0 + j];
            } else if (k0 < 144) {
#pragma unroll
                for (int j = 0; j < 8; ++j) w8[j] = whh[n * 128 + (k0 - 16) + j];
            } else {
#pragma unroll
                for (int j = 0; j < 8; ++j) w8[j] = 0.0f;
            }
            f16x8 hi, lo;
#pragma unroll
            for (int j = 0; j < 8; ++j) {
                f16 h, l;
                split(w8[j], h, l);
                hi[j] = h;
                lo[j] = l;
            }
            wf[tt][kk][0] = hi;
            wf[tt][kk][1] = lo;
        }
    }

    float b_r = 0.f, b_z = 0.f, b_c = 0.f, b_n = 0.f, h = 0.f;
    if (tid < 128) {
        b_r = gb[tid];
        b_z = gb[128 + tid];
        b_c = gb[256 + tid];
        b_n = gbn[tid];
    }
    if (tid < 16) {  // first x (t = 255)
        const float xv = yi[(size_t)b * 4096 + 255 * 16 + tid];
        f16 hi, lo;
        split(xv, hi, lo);
        s_a[0][tid] = hi;
        s_a[1][tid] = lo;
        s_a[2][tid] = hi;
        s_a[3][tid] = lo;
    }
    __syncthreads();

#pragma unroll 1
    for (int ti = 0; ti < 256; ++ti) {
        f32x4 acc[6];
#pragma unroll
        for (int tt = 0; tt < 6; ++tt) acc[tt] = ZC;
#pragma unroll
        for (int kk = 0; kk < 5; ++kk) {
            f16x8 a = {};
            if (col < 4) a = *(const f16x8*)&s_a[col][kk * 32 + quad * 8];
#pragma unroll
            for (int tt = 0; tt < 6; ++tt) {
                acc[tt] = MFMA16(a, wf[tt][kk][0], acc[tt]);
                acc[tt] = MFMA16(a, wf[tt][kk][1], acc[tt]);
            }
        }
        if (quad == 0) {
#pragma unroll
            for (int tt = 0; tt < 6; ++tt) {
                const int n = (wave * 6 + tt) * 16 + col;
                s_sum[n] = acc[tt][0] + acc[tt][1];  // ig+hg
                s_icc[n] = acc[tt][2] + acc[tt][3];  // ig only
            }
        }
        __syncthreads();
        if (tid < 128) {
            const float r = fsig(s_sum[tid] + b_r);
            const float z = fsig(s_sum[128 + tid] + b_z);
            const float ic = s_icc[256 + tid] + b_c;
            const float hn = (s_sum[256 + tid] - s_icc[256 + tid]) + b_n;
            const float nn = ftanh(ic + r * hn);
            h = nn + z * (h - nn);
            f16 hh, hl;
            split(h, hh, hl);
            s_a[0][16 + tid] = hh;
            s_a[1][16 + tid] = hl;
        }
        if (tid < 16 && ti < 255) {
            const float xv = yi[(size_t)b * 4096 + (254 - ti) * 16 + tid];
            f16 hi, lo;
            split(xv, hi, lo);
            s_a[0][tid] = hi;
            s_a[1][tid] = lo;
            s_a[2][tid] = hi;
            s_a[3][tid] = lo;
        }
        __syncthreads();
    }

    if (tid < 128) s_h[tid] = h;
    __syncthreads();

    // ----- h2o MLP, f32 VALU -----
    float a1 = hb1[tid];
    {
        const float* w = hW1 + (size_t)tid * 128;
#pragma unroll 8
        for (int p = 0; p < 128; ++p) a1 += w[p] * s_h[p];
        a1 = ftanh(a1);
    }
    s_t[tid] = a1;
    __syncthreads();
    float a2 = hb2[tid];
    {
        const float* w = hW2 + (size_t)tid * 256;
#pragma unroll 8
        for (int p = 0; p < 256; ++p) a2 += w[p] * s_t[p];
        a2 = ftanh(a2);
    }
    __syncthreads();
    s_t[tid] = a2;
    __syncthreads();
    if (tid < 32) {
        float a3 = hb3[tid];
        const float* w = hW3 + (size_t)tid * 256;
#pragma unroll 8
        for (int p = 0; p < 256; ++p) a3 += w[p] * s_t[p];
        ys[(size_t)b * 32 + tid] = packf16(a3);
    }
}

// =====================================================================
// Kernel 2: Tsit5, one WG (256 thr = 4 waves, 1/SIMD) per batch row.
// Wave w owns outputs 64w..64w+63 (tiles 4w..4w+3) of L0/L1/L2; its L3
// K-chunk is exactly those 64 x2 comps -> no shared x2, no extra barrier.
// All-lane epilogues: lane <-> component wave*64+lane (quad = tile, via
// static selects). 3 barriers per feval.
// =====================================================================
__global__ __launch_bounds__(256, 1) void ode_kernel(
    const float* __restrict__ ts,  // [256]
    const float* __restrict__ W0,  // [256,32]
    const float* __restrict__ W1,  // [256,256]
    const float* __restrict__ W2,  // [256,256]
    const float* __restrict__ Wo,  // [32,256]
    u32* __restrict__ ys)          // [256,256,32] packed
{
    const int b = blockIdx.x;
    const int tid = threadIdx.x;
    const int wave = tid >> 6;   // 0..3
    const int lane = tid & 63;
    const int quad = lane >> 4;
    const int col = lane & 15;
    const int cidx = lane & 31;          // k/y component for update phase
    const int xcomp = wave * 64 + lane;  // this lane's x-output component

    __shared__ alignas(16) f16 s_x0[2][256];      // shared x0 (hi/lo)
    __shared__ alignas(16) f16 s_x1[2][256];      // shared x1
    __shared__ alignas(16) f16 s_x2w[4][2][64];   // per-wave x2
    __shared__ alignas(16) f16 s_yw[4][2][32];    // per-wave y
    __shared__ float s_part[4][33];               // k partials (padded)
    __shared__ float s_ts[256];

    s_ts[tid] = ts[tid];

    const f32x4 ZC = {0.f, 0.f, 0.f, 0.f};

    // ---- weight fragments: 4 n-tiles per wave ----
    f16x8 w0f[4][2], w1f[4][8], w2f[4][8], wof[2][2][2];
#pragma unroll
    for (int tt = 0; tt < 4; ++tt) {
        const int n = (wave * 4 + tt) * 16 + col;
        {
            f16x8 hi, lo;
#pragma unroll
            for (int j = 0; j < 8; ++j) {
                f16 h, l;
                split(W0[n * 32 + quad * 8 + j], h, l);
                hi[j] = h;
                lo[j] = l;
            }
            w0f[tt][0] = hi;
            w0f[tt][1] = lo;
        }
#pragma unroll
        for (int kk = 0; kk < 8; ++kk) {
            f16x8 h1, h2;
#pragma unroll
            for (int j = 0; j < 8; ++j) {
                h1[j] = (f16)W1[n * 256 + kk * 32 + quad * 8 + j];
                h2[j] = (f16)W2[n * 256 + kk * 32 + quad * 8 + j];
            }
            w1f[tt][kk] = h1;
            w2f[tt][kk] = h2;
        }
    }
    // L3: Wout rows 0..31 (2 tiles), K-chunk = wave*64 (2 local kk), hi+lo
#pragma unroll
    for (int tt = 0; tt < 2; ++tt) {
        const int n3 = tt * 16 + col;
#pragma unroll
        for (int kkl = 0; kkl < 2; ++kkl) {
            f16x8 hi, lo;
#pragma unroll
            for (int j = 0; j < 8; ++j) {
                f16 h, l;
                split(Wo[n3 * 256 + wave * 64 + kkl * 32 + quad * 8 + j], h, l);
                hi[j] = h;
                lo[j] = l;
            }
            wof[tt][kkl][0] = hi;
            wof[tt][kkl][1] = lo;
        }
    }

    // ---- initial y ----
    float ybase;
    {
        const u32 p = ys[(size_t)b * 32 + cidx];
        const f16 yh = bitsf16((u16)(p & 0xffffu));
        const f16 yl = bitsf16((u16)(p >> 16));
        ybase = (float)yh + (float)yl;
        s_yw[wave][lane >> 5][cidx] = (lane < 32) ? yh : yl;
    }
    float k_hist[6];
#pragma unroll
    for (int i = 0; i < 6; ++i) k_hist[i] = 0.0f;

    __syncthreads();  // s_ts ready (s_yw is per-wave, DS in-order)

    // L0 for the current per-wave y, producing this lane's x0 component.
    auto do_L0_x0 = [&]() {
        const f16x8 a = *(const f16x8*)&s_yw[wave][col & 1][quad * 8];
        f32x4 c0 = MFMA16(a, w0f[0][0], ZC);
        c0 = MFMA16(a, w0f[0][1], c0);
        f32x4 c1 = MFMA16(a, w0f[1][0], ZC);
        c1 = MFMA16(a, w0f[1][1], c1);
        f32x4 c2 = MFMA16(a, w0f[2][0], ZC);
        c2 = MFMA16(a, w0f[2][1], c2);
        f32x4 c3 = MFMA16(a, w0f[3][0], ZC);
        c3 = MFMA16(a, w0f[3][1], c3);
        const float e0 = c0[0] + c0[1], e1 = c1[0] + c1[1];
        const float e2 = c2[0] + c2[1], e3 = c3[0] + c3[1];
        const float ea = (quad & 1) ? e1 : e0;
        const float eb = (quad & 1) ? e3 : e2;
        const float x = ftanh((quad & 2) ? eb : ea);
        const f16 xh = (f16)x;
        s_x0[0][xcomp] = xh;
        s_x0[1][xcomp] = (f16)(x - (float)xh);
    };

    do_L0_x0();
    __syncthreads();

#pragma unroll 1
    for (int t = 0; t < 255; ++t) {
        const float hstep = s_ts[t + 1] - s_ts[t];
#pragma unroll
        for (int s = 0; s < 6; ++s) {
            // ---- Seg A: x1 = tanh(x0 @ W1^T), K=256 ----
            {
                f32x4 c0 = ZC, c1 = ZC, c2 = ZC, c3 = ZC;
#pragma unroll
                for (int kk = 0; kk < 8; ++kk) {
                    const f16x8 a = *(const f16x8*)&s_x0[col & 1][kk * 32 + quad * 8];
                    c0 = MFMA16(a, w1f[0][kk], c0);
                    c1 = MFMA16(a, w1f[1][kk], c1);
                    c2 = MFMA16(a, w1f[2][kk], c2);
                    c3 = MFMA16(a, w1f[3][kk], c3);
                }
                const float e0 = c0[0] + c0[1], e1 = c1[0] + c1[1];
                const float e2 = c2[0] + c2[1], e3 = c3[0] + c3[1];
                const float ea = (quad & 1) ? e1 : e0;
                const float eb = (quad & 1) ? e3 : e2;
                const float x = ftanh((quad & 2) ? eb : ea);
                const f16 xh = (f16)x;
                s_x1[0][xcomp] = xh;
                s_x1[1][xcomp] = (f16)(x - (float)xh);
            }
            __syncthreads();
            // ---- Seg B: x2 = tanh(x1 @ W2^T); then L3 partial from own chunk ----
            {
                f32x4 c0 = ZC, c1 = ZC, c2 = ZC, c3 = ZC;
#pragma unroll
                for (int kk = 0; kk < 8; ++kk) {
                    const f16x8 a = *(const f16x8*)&s_x1[col & 1][kk * 32 + quad * 8];
                    c0 = MFMA16(a, w2f[0][kk], c0);
                    c1 = MFMA16(a, w2f[1][kk], c1);
                    c2 = MFMA16(a, w2f[2][kk], c2);
                    c3 = MFMA16(a, w2f[3][kk], c3);
                }
                const float e0 = c0[0] + c0[1], e1 = c1[0] + c1[1];
                const float e2 = c2[0] + c2[1], e3 = c3[0] + c3[1];
                const float ea = (quad & 1) ? e1 : e0;
                const float eb = (quad & 1) ? e3 : e2;
                const float x = ftanh((quad & 2) ? eb : ea);
                const f16 xh = (f16)x;
                s_x2w[wave][0][lane] = xh;
                s_x2w[wave][1][lane] = (f16)(x - (float)xh);
                // L3 partial: K-chunk = this wave's 64 comps (DS in-order, no barrier)
                const f16x8 a0 = *(const f16x8*)&s_x2w[wave][col & 1][quad * 8];
                const f16x8 a1 = *(const f16x8*)&s_x2w[wave][col & 1][32 + quad * 8];
                f32x4 p0 = MFMA16(a0, wof[0][0][0], ZC);
                p0 = MFMA16(a0, wof[0][0][1], p0);
                p0 = MFMA16(a1, wof[0][1][0], p0);
                p0 = MFMA16(a1, wof[0][1][1], p0);
                f32x4 p1 = MFMA16(a0, wof[1][0][0], ZC);
                p1 = MFMA16(a0, wof[1][0][1], p1);
                p1 = MFMA16(a1, wof[1][1][0], p1);
                p1 = MFMA16(a1, wof[1][1][1], p1);
                if (quad == 0) s_part[wave][col] = p0[0] + p0[1];
                if (quad == 1) s_part[wave][16 + col] = p1[0] + p1[1];
            }
            __syncthreads();
            // ---- Seg C: reduce + tableau update + L0 for next argument ----
            {
                const float kv = s_part[0][cidx] + s_part[1][cidx] +
                                 s_part[2][cidx] + s_part[3][cidx];
                k_hist[s] = kv;
                float sum = 0.0f;
#pragma unroll
                for (int i = 0; i < 6; ++i)
                    if (i <= s) sum += cAc[s][i] * k_hist[i];
                const float v = ybase + hstep * sum;
                if (s == 5) {
                    ybase = v;
                    if (tid < 32)
                        ys[((size_t)(t + 1) * 256 + b) * 32 + cidx] = packf16(v);
                }
                const f16 vh = (f16)v;
                s_yw[wave][lane >> 5][cidx] = (lane < 32) ? vh : (f16)(v - (float)vh);
                do_L0_x0();  // same-wave y roundtrip, DS in-order
            }
            __syncthreads();
        }
    }
}

// =====================================================================
// Kernel 3: o2d MLP (identity), f16 MFMA, (A_hi+A_lo)(B_hi+B_lo).
// 16 rows of flattened [T*B] per WG. Output f32.
// =====================================================================
__global__ __launch_bounds__(256, 1) void o2d_kernel(
    const u32* __restrict__ ys,  // [T*B, 32] packed f16 hi|lo
    const float* __restrict__ W1, const float* __restrict__ b1,  // [256,32],[256]
    const float* __restrict__ W2, const float* __restrict__ b2,  // [256,256],[256]
    const float* __restrict__ W3, const float* __restrict__ b3,  // [16,256],[16]
    float* __restrict__ out)  // [B,T,16]
{
    const int r0 = blockIdx.x * 16;
    const int tid = threadIdx.x;
    const int wave = tid >> 6;
    const int lane = tid & 63;
    const int quad = lane >> 4;
    const int col = lane & 15;

    __shared__ alignas(16) f16 s_a[2][16][32];
    __shared__ alignas(16) f16 s_x[2][2][16][264];
    __shared__ float s_part[4][16][16];

    const f32x4 ZC = {0.f, 0.f, 0.f, 0.f};

    f16x8 w1f[4][2], w2f[4][8][2], w3f[2][2];
    float b1r[4], b2r[4];
#pragma unroll
    for (int tt = 0; tt < 4; ++tt) {
        const int n = (wave * 4 + tt) * 16 + col;
        b1r[tt] = b1[n];
        b2r[tt] = b2[n];
        {
            f16x8 hi, lo;
#pragma unroll
            for (int j = 0; j < 8; ++j) {
                f16 h, l;
                split(W1[n * 32 + quad * 8 + j], h, l);
                hi[j] = h;
                lo[j] = l;
            }
            w1f[tt][0] = hi;
            w1f[tt][1] = lo;
        }
#pragma unroll
        for (int kk = 0; kk < 8; ++kk) {
            f16x8 hi, lo;
#pragma unroll
            for (int j = 0; j < 8; ++j) {
                f16 h, l;
                split(W2[n * 256 + kk * 32 + quad * 8 + j], h, l);
                hi[j] = h;
                lo[j] = l;
            }
            w2f[tt][kk][0] = hi;
            w2f[tt][kk][1] = lo;
        }
    }
#pragma unroll
    for (int c = 0; c < 2; ++c) {
        const int kk = wave * 2 + c;
        f16x8 hi, lo;
#pragma unroll
        for (int j = 0; j < 8; ++j) {
            f16 h, l;
            split(W3[col * 256 + kk * 32 + quad * 8 + j], h, l);
            hi[j] = h;
            lo[j] = l;
        }
        w3f[c][0] = hi;
        w3f[c][1] = lo;
    }

    {  // stage ys rows (unpack f16 hi/lo)
        const int row = tid >> 4;
        const int k2 = (tid & 15) * 2;
        const u32 p0 = ys[(size_t)(r0 + row) * 32 + k2];
        const u32 p1 = ys[(size_t)(r0 + row) * 32 + k2 + 1];
        s_a[0][row][k2] = bitsf16((u16)(p0 & 0xffffu));
        s_a[0][row][k2 + 1] = bitsf16((u16)(p1 & 0xffffu));
        s_a[1][row][k2] = bitsf16((u16)(p0 >> 16));
        s_a[1][row][k2 + 1] = bitsf16((u16)(p1 >> 16));
    }
    __syncthreads();

    f32x4 acc[4];
    // ---- L1: K=32 ----
#pragma unroll
    for (int tt = 0; tt < 4; ++tt) acc[tt] = ZC;
#pragma unroll
    for (int hl = 0; hl < 2; ++hl) {
        const f16x8 a = *(const f16x8*)&s_a[hl][col][quad * 8];
#pragma unroll
        for (int bl = 0; bl < 2; ++bl)
#pragma unroll
            for (int tt = 0; tt < 4; ++tt) acc[tt] = MFMA16(a, w1f[tt][bl], acc[tt]);
    }
#pragma unroll
    for (int tt = 0; tt < 4; ++tt) {
        const int n = (wave * 4 + tt) * 16 + col;
#pragma unroll
        for (int rg = 0; rg < 4; ++rg) {
            const int row = quad * 4 + rg;
            const float v = acc[tt][rg] + b1r[tt];
            f16 hi, lo;
            split(v, hi, lo);
            s_x[0][0][row][n] = hi;
            s_x[0][1][row][n] = lo;
        }
    }
    __syncthreads();
    // ---- L2: K=256 ----
#pragma unroll
    for (int tt = 0; tt < 4; ++tt) acc[tt] = ZC;
#pragma unroll
    for (int kk = 0; kk < 8; ++kk) {
#pragma unroll
        for (int hl = 0; hl < 2; ++hl) {
            const f16x8 a = *(const f16x8*)&s_x[0][hl][col][kk * 32 + quad * 8];
#pragma unroll
            for (int bl = 0; bl < 2; ++bl)
#pragma unroll
                for (int tt = 0; tt < 4; ++tt) acc[tt] = MFMA16(a, w2f[tt][kk][bl], acc[tt]);
        }
    }
#pragma unroll
    for (int tt = 0; tt < 4; ++tt) {
        const int n = (wave * 4 + tt) * 16 + col;
#pragma unroll
        for (int rg = 0; rg < 4; ++rg) {
            const int row = quad * 4 + rg;
            const float v = acc[tt][rg] + b2r[tt];
            f16 hi, lo;
            split(v, hi, lo);
            s_x[1][0][row][n] = hi;
            s_x[1][1][row][n] = lo;
        }
    }
    __syncthreads();
    // ---- L3: N=16, K split over waves ----
    f32x4 a3 = ZC;
#pragma unroll
    for (int c = 0; c < 2; ++c) {
        const int kk = wave * 2 + c;
#pragma unroll
        for (int hl = 0; hl < 2; ++hl) {
            const f16x8 a = *(const f16x8*)&s_x[1][hl][col][kk * 32 + quad * 8];
#pragma unroll
            for (int bl = 0; bl < 2; ++bl) a3 = MFMA16(a, w3f[c][bl], a3);
        }
    }
#pragma unroll
    for (int rg = 0; rg < 4; ++rg) s_part[wave][quad * 4 + rg][col] = a3[rg];
    __syncthreads();
    {
        const int row = tid >> 4;
        const int cc = tid & 15;
        const float v = s_part[0][row][cc] + s_part[1][row][cc] + s_part[2][row][cc] +
                        s_part[3][row][cc] + b3[cc];
        const int r = r0 + row;
        const int bb = r & 255;   // batch index
        const int tt2 = r >> 8;   // time index
        out[((size_t)bb * 256 + tt2) * 16 + cc] = v;
    }
}

// =====================================================================
extern "C" void kernel_launch(void* const* d_in, const int* in_sizes, int n_in,
                              void* d_out, int out_size, void* d_ws, size_t ws_size,
                              hipStream_t stream) {
    (void)in_sizes; (void)n_in; (void)out_size; (void)ws_size;
    const float* ts      = (const float*)d_in[0];
    const float* yi      = (const float*)d_in[1];
    const float* gru_wih = (const float*)d_in[2];
    const float* gru_whh = (const float*)d_in[3];
    const float* gru_b   = (const float*)d_in[4];
    const float* gru_bn  = (const float*)d_in[5];
    const float* h2o_W1  = (const float*)d_in[6];
    const float* h2o_b1  = (const float*)d_in[7];
    const float* h2o_W2  = (const float*)d_in[8];
    const float* h2o_b2  = (const float*)d_in[9];
    const float* h2o_W3  = (const float*)d_in[10];
    const float* h2o_b3  = (const float*)d_in[11];
    const float* cf_W0   = (const float*)d_in[12];
    const float* cf_W1   = (const float*)d_in[13];
    const float* cf_W2   = (const float*)d_in[14];
    const float* cf_Wout = (const float*)d_in[15];
    const float* o2d_W1  = (const float*)d_in[16];
    const float* o2d_b1  = (const float*)d_in[17];
    const float* o2d_W2  = (const float*)d_in[18];
    const float* o2d_b2  = (const float*)d_in[19];
    const float* o2d_W3  = (const float*)d_in[20];
    const float* o2d_b3  = (const float*)d_in[21];

    u32* ys = (u32*)d_ws;  // [256,256,32] packed f16 (hi | lo<<16) = 4 MB

    gru_h2o_kernel<<<256, 256, 0, stream>>>(yi, gru_wih, gru_whh, gru_b, gru_bn,
                                            h2o_W1, h2o_b1, h2o_W2, h2o_b2, h2o_W3, h2o_b3, ys);
    ode_kernel<<<256, 256, 0, stream>>>(ts, cf_W0, cf_W1, cf_W2, cf_Wout, ys);
    o2d_kernel<<<4096, 256, 0, stream>>>(ys, o2d_W1, o2d_b1, o2d_W2, o2d_b2,
                                         o2d_W3, o2d_b3, (float*)d_out);
}

// Round 8
// 2251.759 us; speedup vs baseline: 1.3608x; 1.3608x over previous
//
#include <hip/hip_runtime.h>

// NeuralODE, ALL-F32 I/O.
// GRU: 512 thr, 8 waves (2/SIMD), in-wave gates (wave w owns gate tiles
//   {w,w+8,w+16}), 1 barrier/step, x-prefetch. f16 MFMA hi/lo.
// h2o MLP: f32 VALU. o2d MLP: f16 MFMA hi/lo.
// Tsit5 x255: 512 thr (8 waves, 2/SIMD), 3 barriers/feval:
//   [L1][L2+per-wave L3 partial][reduce+update+L0]. W1/W2 hi-only in VGPRs,
//   W0/Wout hi+lo. Activations as f16 hi/lo A-rows (col&1 broadcast).
// ys workspace: u32-packed f16 (hi | lo<<16) = 4 MB.

typedef unsigned short u16;
typedef unsigned int u32;
typedef _Float16 f16;
typedef __attribute__((ext_vector_type(8))) _Float16 f16x8;
typedef __attribute__((ext_vector_type(4))) float f32x4;

#define MFMA16(A, B, C) __builtin_amdgcn_mfma_f32_16x16x32_f16((A), (B), (C), 0, 0, 0)

__device__ __forceinline__ u16 f16bits(f16 h) { union { f16 f; u16 u; } c; c.f = h; return c.u; }
__device__ __forceinline__ f16 bitsf16(u16 u) { union { f16 f; u16 u; } c; c.u = u; return c.f; }
__device__ __forceinline__ void split(float v, f16& hi, f16& lo) {
    hi = (f16)v;
    lo = (f16)(v - (float)hi);
}
__device__ __forceinline__ u32 packf16(float v) {
    f16 hi, lo;
    split(v, hi, lo);
    return (u32)f16bits(hi) | ((u32)f16bits(lo) << 16);
}
__device__ __forceinline__ float fsig(float x) { return 1.0f / (1.0f + __expf(-x)); }
__device__ __forceinline__ float ftanh(float x) {
    float e = __expf(2.0f * x);
    return 1.0f - 2.0f / (e + 1.0f);
}

// Tsit5 tableau: rows 0..4 = stage-argument coefficients, row 5 = final update.
constexpr float cAc[6][6] = {
    {0.161f, 0.f, 0.f, 0.f, 0.f, 0.f},
    {-0.008480655492356989f, 0.335480655492357f, 0.f, 0.f, 0.f, 0.f},
    {2.8971530571054935f, -6.359448489975075f, 4.3622954328695815f, 0.f, 0.f, 0.f},
    {5.325864828439257f, -11.748883564062828f, 7.4955393428898365f, -0.09249506636175525f, 0.f, 0.f},
    {5.86145544294642f, -12.92096931784711f, 8.159367898576159f, -0.071584973281401f, -0.028269050394068383f, 0.f},
    {0.09646076681806523f, 0.01f, 0.4798896504144996f, 1.379008574103742f, -3.290069515436081f, 2.324710524099774f}};

// =====================================================================
// Kernel 1: GRU, 512 thr / 8 waves, in-wave gates, 1 barrier per step.
// Wave w owns gate tiles {w, w+8, w+16} (r/z/c rows 16w.., 128+16w..,
// 256+16w..). A-row broadcast col&3 => every quad's acc regs 0..3 hold
// D rows 0..3 = [(x|h)hi, (x|h)lo, x-hi, x-lo] dots for n = tile*16+col.
// Gates for h-comp 16w+col computed identically in all lanes; quad0
// writes h to the ping-pong A buffer. Then h2o MLP (f32, tid<256).
// =====================================================================
__global__ __launch_bounds__(512, 2) void gru_h2o_kernel(
    const float* __restrict__ yi,   // [256,256,16]
    const float* __restrict__ wih,  // [384,16]
    const float* __restrict__ whh,  // [384,128]
    const float* __restrict__ gb,   // [384]
    const float* __restrict__ gbn,  // [128]
    const float* __restrict__ hW1, const float* __restrict__ hb1,  // [256,128],[256]
    const float* __restrict__ hW2, const float* __restrict__ hb2,  // [256,256],[256]
    const float* __restrict__ hW3, const float* __restrict__ hb3,  // [32,256],[32]
    u32* __restrict__ ys)  // [256,256,32] packed f16 hi|lo; writes ys[0]
{
    const int b = blockIdx.x;
    const int tid = threadIdx.x;
    const int wave = tid >> 6;   // 0..7
    const int lane = tid & 63;
    const int quad = lane >> 4;
    const int col = lane & 15;
    const int j = wave * 16 + col;  // this lane's h-component

    // A rows: 0=(x|h)hi 1=(x|h)lo 2=(x|0)hi 3=(x|0)lo ; K=160 (16 x | 128 h | 16 pad)
    __shared__ alignas(16) f16 s_a[2][4][160];  // ping-pong
    __shared__ float s_h[128];
    __shared__ float s_t[256];

    const f32x4 ZC = {0.f, 0.f, 0.f, 0.f};

    // ---- weight fragments: tiles w, w+8, w+16 ----
    f16x8 wf[3][5][2];
#pragma unroll
    for (int tt = 0; tt < 3; ++tt) {
        const int n = (wave + tt * 8) * 16 + col;
#pragma unroll
        for (int kk = 0; kk < 5; ++kk) {
            const int k0 = kk * 32 + quad * 8;
            float w8[8];
            if (k0 < 16) {
#pragma unroll
                for (int jj = 0; jj < 8; ++jj) w8[jj] = wih[n * 16 + k0 + jj];
            } else if (k0 < 144) {
#pragma unroll
                for (int jj = 0; jj < 8; ++jj) w8[jj] = whh[n * 128 + (k0 - 16) + jj];
            } else {
#pragma unroll
                for (int jj = 0; jj < 8; ++jj) w8[jj] = 0.0f;
            }
            f16x8 hi, lo;
#pragma unroll
            for (int jj = 0; jj < 8; ++jj) {
                f16 h, l;
                split(w8[jj], h, l);
                hi[jj] = h;
                lo[jj] = l;
            }
            wf[tt][kk][0] = hi;
            wf[tt][kk][1] = lo;
        }
    }

    const float b_r = gb[j];
    const float b_z = gb[128 + j];
    const float b_c = gb[256 + j];
    const float b_n = gbn[j];

    // zero both buffers (covers pad and h-region of rows 2/3)
    for (int i = tid; i < 2 * 4 * 160; i += 512) ((f16*)s_a)[i] = (f16)0.0f;
    __syncthreads();
    if (tid < 16) {  // first x (t = 255) into buffer 0
        const float xv = yi[(size_t)b * 4096 + 255 * 16 + tid];
        f16 hi, lo;
        split(xv, hi, lo);
        s_a[0][0][tid] = hi;
        s_a[0][1][tid] = lo;
        s_a[0][2][tid] = hi;
        s_a[0][3][tid] = lo;
    }
    __syncthreads();

    float h = 0.0f;
#pragma unroll 1
    for (int ti = 0; ti < 256; ++ti) {
        const int p = ti & 1;
        const int np = 1 - p;
        // prefetch next x early (consumed after gates)
        float xnext = 0.0f;
        if (tid < 16 && ti < 255) xnext = yi[(size_t)b * 4096 + (254 - ti) * 16 + tid];

        f32x4 a0 = ZC, a1 = ZC, a2 = ZC;
#pragma unroll
        for (int kk = 0; kk < 5; ++kk) {
            const f16x8 a = *(const f16x8*)&s_a[p][col & 3][kk * 32 + quad * 8];
            a0 = MFMA16(a, wf[0][kk][0], a0);
            a0 = MFMA16(a, wf[0][kk][1], a0);
            a1 = MFMA16(a, wf[1][kk][0], a1);
            a1 = MFMA16(a, wf[1][kk][1], a1);
            a2 = MFMA16(a, wf[2][kk][0], a2);
            a2 = MFMA16(a, wf[2][kk][1], a2);
        }
        // gates — identical in all lanes of the wave (quads are copies)
        {
            const float sum_r = a0[0] + a0[1];
            const float sum_z = a1[0] + a1[1];
            const float sum_c = a2[0] + a2[1];  // full (x|h)
            const float icc = a2[2] + a2[3];    // x-only
            const float r = fsig(sum_r + b_r);
            const float z = fsig(sum_z + b_z);
            const float ic = icc + b_c;
            const float hn = (sum_c - icc) + b_n;
            const float nn = ftanh(ic + r * hn);
            h = nn + z * (h - nn);
        }
        if (quad == 0) {  // write h (hi/lo) for next step
            f16 hh, hl;
            split(h, hh, hl);
            s_a[np][0][16 + j] = hh;
            s_a[np][1][16 + j] = hl;
        }
        if (tid < 16 && ti < 255) {  // stage next x
            f16 hi, lo;
            split(xnext, hi, lo);
            s_a[np][0][tid] = hi;
            s_a[np][1][tid] = lo;
            s_a[np][2][tid] = hi;
            s_a[np][3][tid] = lo;
        }
        __syncthreads();
    }

    if (quad == 0) s_h[j] = h;
    __syncthreads();

    // ----- h2o MLP, f32 VALU (tid < 256) -----
    float a1v = 0.0f;
    if (tid < 256) {
        a1v = hb1[tid];
        const float* w = hW1 + (size_t)tid * 128;
#pragma unroll 8
        for (int p = 0; p < 128; ++p) a1v += w[p] * s_h[p];
        a1v = ftanh(a1v);
        s_t[tid] = a1v;
    }
    __syncthreads();
    float a2v = 0.0f;
    if (tid < 256) {
        a2v = hb2[tid];
        const float* w = hW2 + (size_t)tid * 256;
#pragma unroll 8
        for (int p = 0; p < 256; ++p) a2v += w[p] * s_t[p];
        a2v = ftanh(a2v);
    }
    __syncthreads();
    if (tid < 256) s_t[tid] = a2v;
    __syncthreads();
    if (tid < 32) {
        float a3 = hb3[tid];
        const float* w = hW3 + (size_t)tid * 256;
#pragma unroll 8
        for (int p = 0; p < 256; ++p) a3 += w[p] * s_t[p];
        ys[(size_t)b * 32 + tid] = packf16(a3);
    }
}

// =====================================================================
// Kernel 2: Tsit5, one WG (512 thr = 8 waves, 2/SIMD) per batch row.
// Wave w owns n-tiles 2w,2w+1 (outputs 32w..32w+31) for L0/L1/L2; its L3
// K-chunk = those same 32 x2 comps via per-wave LDS (no barrier).
// 3 barriers/feval: [L1][L2+L3part][reduce+update+L0].
// =====================================================================
__global__ __launch_bounds__(512, 2) void ode_kernel(
    const float* __restrict__ ts,  // [256]
    const float* __restrict__ W0,  // [256,32]
    const float* __restrict__ W1,  // [256,256]
    const float* __restrict__ W2,  // [256,256]
    const float* __restrict__ Wo,  // [32,256]
    u32* __restrict__ ys)          // [256,256,32] packed
{
    const int b = blockIdx.x;
    const int tid = threadIdx.x;
    const int wave = tid >> 6;   // 0..7
    const int lane = tid & 63;
    const int quad = lane >> 4;
    const int col = lane & 15;
    const int half = quad >> 1;        // 0 or 1
    const int hl = quad & 1;           // 0 = hi, 1 = lo
    const int cidx = col + half * 16;  // y/k component (0..31)

    __shared__ alignas(16) f16 s_x0[2][256];
    __shared__ alignas(16) f16 s_x1[2][256];
    __shared__ alignas(16) f16 s_x2w[8][2][32];  // per-wave x2 (own 32 comps)
    __shared__ alignas(16) f16 s_yw[8][2][32];   // per-wave private y
    __shared__ float s_part[8][32];
    __shared__ float s_ts[256];

    if (tid < 256) s_ts[tid] = ts[tid];

    const f32x4 ZC = {0.f, 0.f, 0.f, 0.f};

    // ---- weight fragments (per wave: n-tiles 2w, 2w+1) ----
    f16x8 w0f[2][2], w1f[2][8], w2f[2][8], wof[2][2];
#pragma unroll
    for (int tt = 0; tt < 2; ++tt) {
        const int n = (wave * 2 + tt) * 16 + col;
        {
            f16x8 hi, lo;
#pragma unroll
            for (int jj = 0; jj < 8; ++jj) {
                f16 h, l;
                split(W0[n * 32 + quad * 8 + jj], h, l);
                hi[jj] = h;
                lo[jj] = l;
            }
            w0f[tt][0] = hi;
            w0f[tt][1] = lo;
        }
#pragma unroll
        for (int kk = 0; kk < 8; ++kk) {
            f16x8 h1, h2;
#pragma unroll
            for (int jj = 0; jj < 8; ++jj) {
                h1[jj] = (f16)W1[n * 256 + kk * 32 + quad * 8 + jj];
                h2[jj] = (f16)W2[n * 256 + kk * 32 + quad * 8 + jj];
            }
            w1f[tt][kk] = h1;
            w2f[tt][kk] = h2;
        }
        // L3: Wout rows tt*16+col, K-chunk = wave*32, hi+lo
        {
            const int n3 = tt * 16 + col;
            f16x8 hi, lo;
#pragma unroll
            for (int jj = 0; jj < 8; ++jj) {
                f16 h, l;
                split(Wo[n3 * 256 + wave * 32 + quad * 8 + jj], h, l);
                hi[jj] = h;
                lo[jj] = l;
            }
            wof[tt][0] = hi;
            wof[tt][1] = lo;
        }
    }

    // ---- initial y ----
    float ybase;
    {
        const u32 p = ys[(size_t)b * 32 + cidx];
        const f16 yh = bitsf16((u16)(p & 0xffffu));
        const f16 yl = bitsf16((u16)(p >> 16));
        ybase = (float)yh + (float)yl;
        s_yw[wave][hl][cidx] = hl ? yl : yh;
    }
    float k_hist[6];
#pragma unroll
    for (int i = 0; i < 6; ++i) k_hist[i] = 0.0f;

    __syncthreads();  // s_ts ready (s_yw per-wave, DS in-order)

    // L0 from this wave's private y -> this lane's x0 component
    auto do_L0_x0 = [&]() {
        const f16x8 a = *(const f16x8*)&s_yw[wave][col & 1][quad * 8];
        f32x4 aA = MFMA16(a, w0f[0][0], ZC);
        aA = MFMA16(a, w0f[0][1], aA);
        f32x4 aB = MFMA16(a, w0f[1][0], ZC);
        aB = MFMA16(a, w0f[1][1], aB);
        const float e = half ? (aB[0] + aB[1]) : (aA[0] + aA[1]);
        const float x = ftanh(e);
        const f16 xh = (f16)x;
        s_x0[hl][(wave * 2 + half) * 16 + col] = hl ? (f16)(x - (float)xh) : xh;
    };

    do_L0_x0();
    __syncthreads();

#pragma unroll 1
    for (int t = 0; t < 255; ++t) {
        const float hstep = s_ts[t + 1] - s_ts[t];
#pragma unroll
        for (int s = 0; s < 6; ++s) {
            // ---- Seg 1: x1 = tanh(x0 @ W1^T), K=256, even/odd split chains ----
            {
                f32x4 e0 = ZC, e1 = ZC, o0 = ZC, o1 = ZC;
#pragma unroll
                for (int kk = 0; kk < 8; kk += 2) {
                    const f16x8 ae = *(const f16x8*)&s_x0[col & 1][kk * 32 + quad * 8];
                    const f16x8 ao = *(const f16x8*)&s_x0[col & 1][(kk + 1) * 32 + quad * 8];
                    e0 = MFMA16(ae, w1f[0][kk], e0);
                    e1 = MFMA16(ae, w1f[1][kk], e1);
                    o0 = MFMA16(ao, w1f[0][kk + 1], o0);
                    o1 = MFMA16(ao, w1f[1][kk + 1], o1);
                }
                const float e = half ? (e1[0] + e1[1] + o1[0] + o1[1])
                                     : (e0[0] + e0[1] + o0[0] + o0[1]);
                const float x = ftanh(e);
                const f16 xh = (f16)x;
                s_x1[hl][(wave * 2 + half) * 16 + col] = hl ? (f16)(x - (float)xh) : xh;
            }
            __syncthreads();
            // ---- Seg 2: x2 = tanh(x1 @ W2^T) -> per-wave LDS -> own L3 chunk ----
            {
                f32x4 e0 = ZC, e1 = ZC, o0 = ZC, o1 = ZC;
#pragma unroll
                for (int kk = 0; kk < 8; kk += 2) {
                    const f16x8 ae = *(const f16x8*)&s_x1[col & 1][kk * 32 + quad * 8];
                    const f16x8 ao = *(const f16x8*)&s_x1[col & 1][(kk + 1) * 32 + quad * 8];
                    e0 = MFMA16(ae, w2f[0][kk], e0);
                    e1 = MFMA16(ae, w2f[1][kk], e1);
                    o0 = MFMA16(ao, w2f[0][kk + 1], o0);
                    o1 = MFMA16(ao, w2f[1][kk + 1], o1);
                }
                const float e = half ? (e1[0] + e1[1] + o1[0] + o1[1])
                                     : (e0[0] + e0[1] + o0[0] + o0[1]);
                const float x = ftanh(e);
                const f16 xh = (f16)x;
                s_x2w[wave][hl][half * 16 + col] = hl ? (f16)(x - (float)xh) : xh;
                // L3 partial from own K-chunk (same-wave DS, no barrier)
                const f16x8 a = *(const f16x8*)&s_x2w[wave][col & 1][quad * 8];
                f32x4 p0 = MFMA16(a, wof[0][0], ZC);
                p0 = MFMA16(a, wof[0][1], p0);
                f32x4 p1 = MFMA16(a, wof[1][0], ZC);
                p1 = MFMA16(a, wof[1][1], p1);
                if (quad == 0) s_part[wave][col] = p0[0] + p0[1];
                if (quad == 1) s_part[wave][16 + col] = p1[0] + p1[1];
            }
            __syncthreads();
            // ---- Seg 3: reduce + tableau update + L0 for next argument ----
            {
                float kv = 0.0f;
#pragma unroll
                for (int p = 0; p < 8; ++p) kv += s_part[p][cidx];
                k_hist[s] = kv;
                float sum = 0.0f;
#pragma unroll
                for (int i = 0; i < 6; ++i)
                    if (i <= s) sum += cAc[s][i] * k_hist[i];
                const float v = ybase + hstep * sum;
                if (s == 5) {
                    ybase = v;
                    if (wave == 0 && !hl)
                        ys[((size_t)(t + 1) * 256 + b) * 32 + cidx] = packf16(v);
                }
                const f16 vh = (f16)v;
                s_yw[wave][hl][cidx] = hl ? (f16)(v - (float)vh) : vh;
                do_L0_x0();  // same-wave y roundtrip, DS in-order
            }
            __syncthreads();
        }
    }
}

// =====================================================================
// Kernel 3: o2d MLP (identity), f16 MFMA, (A_hi+A_lo)(B_hi+B_lo).
// 16 rows of flattened [T*B] per WG. Output f32.
// =====================================================================
__global__ __launch_bounds__(256, 1) void o2d_kernel(
    const u32* __restrict__ ys,  // [T*B, 32] packed f16 hi|lo
    const float* __restrict__ W1, const float* __restrict__ b1,  // [256,32],[256]
    const float* __restrict__ W2, const float* __restrict__ b2,  // [256,256],[256]
    const float* __restrict__ W3, const float* __restrict__ b3,  // [16,256],[16]
    float* __restrict__ out)  // [B,T,16]
{
    const int r0 = blockIdx.x * 16;
    const int tid = threadIdx.x;
    const int wave = tid >> 6;
    const int lane = tid & 63;
    const int quad = lane >> 4;
    const int col = lane & 15;

    __shared__ alignas(16) f16 s_a[2][16][32];
    __shared__ alignas(16) f16 s_x[2][2][16][264];
    __shared__ float s_part[4][16][16];

    const f32x4 ZC = {0.f, 0.f, 0.f, 0.f};

    f16x8 w1f[4][2], w2f[4][8][2], w3f[2][2];
    float b1r[4], b2r[4];
#pragma unroll
    for (int tt = 0; tt < 4; ++tt) {
        const int n = (wave * 4 + tt) * 16 + col;
        b1r[tt] = b1[n];
        b2r[tt] = b2[n];
        {
            f16x8 hi, lo;
#pragma unroll
            for (int jj = 0; jj < 8; ++jj) {
                f16 h, l;
                split(W1[n * 32 + quad * 8 + jj], h, l);
                hi[jj] = h;
                lo[jj] = l;
            }
            w1f[tt][0] = hi;
            w1f[tt][1] = lo;
        }
#pragma unroll
        for (int kk = 0; kk < 8; ++kk) {
            f16x8 hi, lo;
#pragma unroll
            for (int jj = 0; jj < 8; ++jj) {
                f16 h, l;
                split(W2[n * 256 + kk * 32 + quad * 8 + jj], h, l);
                hi[jj] = h;
                lo[jj] = l;
            }
            w2f[tt][kk][0] = hi;
            w2f[tt][kk][1] = lo;
        }
    }
#pragma unroll
    for (int c = 0; c < 2; ++c) {
        const int kk = wave * 2 + c;
        f16x8 hi, lo;
#pragma unroll
        for (int jj = 0; jj < 8; ++jj) {
            f16 h, l;
            split(W3[col * 256 + kk * 32 + quad * 8 + jj], h, l);
            hi[jj] = h;
            lo[jj] = l;
        }
        w3f[c][0] = hi;
        w3f[c][1] = lo;
    }

    {  // stage ys rows (unpack f16 hi/lo)
        const int row = tid >> 4;
        const int k2 = (tid & 15) * 2;
        const u32 p0 = ys[(size_t)(r0 + row) * 32 + k2];
        const u32 p1 = ys[(size_t)(r0 + row) * 32 + k2 + 1];
        s_a[0][row][k2] = bitsf16((u16)(p0 & 0xffffu));
        s_a[0][row][k2 + 1] = bitsf16((u16)(p1 & 0xffffu));
        s_a[1][row][k2] = bitsf16((u16)(p0 >> 16));
        s_a[1][row][k2 + 1] = bitsf16((u16)(p1 >> 16));
    }
    __syncthreads();

    f32x4 acc[4];
    // ---- L1: K=32 ----
#pragma unroll
    for (int tt = 0; tt < 4; ++tt) acc[tt] = ZC;
#pragma unroll
    for (int hl = 0; hl < 2; ++hl) {
        const f16x8 a = *(const f16x8*)&s_a[hl][col][quad * 8];
#pragma unroll
        for (int bl = 0; bl < 2; ++bl)
#pragma unroll
            for (int tt = 0; tt < 4; ++tt) acc[tt] = MFMA16(a, w1f[tt][bl], acc[tt]);
    }
#pragma unroll
    for (int tt = 0; tt < 4; ++tt) {
        const int n = (wave * 4 + tt) * 16 + col;
#pragma unroll
        for (int rg = 0; rg < 4; ++rg) {
            const int row = quad * 4 + rg;
            const float v = acc[tt][rg] + b1r[tt];
            f16 hi, lo;
            split(v, hi, lo);
            s_x[0][0][row][n] = hi;
            s_x[0][1][row][n] = lo;
        }
    }
    __syncthreads();
    // ---- L2: K=256 ----
#pragma unroll
    for (int tt = 0; tt < 4; ++tt) acc[tt] = ZC;
#pragma unroll
    for (int kk = 0; kk < 8; ++kk) {
#pragma unroll
        for (int hl = 0; hl < 2; ++hl) {
            const f16x8 a = *(const f16x8*)&s_x[0][hl][col][kk * 32 + quad * 8];
#pragma unroll
            for (int bl = 0; bl < 2; ++bl)
#pragma unroll
                for (int tt = 0; tt < 4; ++tt) acc[tt] = MFMA16(a, w2f[tt][kk][bl], acc[tt]);
        }
    }
#pragma unroll
    for (int tt = 0; tt < 4; ++tt) {
        const int n = (wave * 4 + tt) * 16 + col;
#pragma unroll
        for (int rg = 0; rg < 4; ++rg) {
            const int row = quad * 4 + rg;
            const float v = acc[tt][rg] + b2r[tt];
            f16 hi, lo;
            split(v, hi, lo);
            s_x[1][0][row][n] = hi;
            s_x[1][1][row][n] = lo;
        }
    }
    __syncthreads();
    // ---- L3: N=16, K split over waves ----
    f32x4 a3 = ZC;
#pragma unroll
    for (int c = 0; c < 2; ++c) {
        const int kk = wave * 2 + c;
#pragma unroll
        for (int hl = 0; hl < 2; ++hl) {
            const f16x8 a = *(const f16x8*)&s_x[1][hl][col][kk * 32 + quad * 8];
#pragma unroll
            for (int bl = 0; bl < 2; ++bl) a3 = MFMA16(a, w3f[c][bl], a3);
        }
    }
#pragma unroll
    for (int rg = 0; rg < 4; ++rg) s_part[wave][quad * 4 + rg][col] = a3[rg];
    __syncthreads();
    {
        const int row = tid >> 4;
        const int cc = tid & 15;
        const float v = s_part[0][row][cc] + s_part[1][row][cc] + s_part[2][row][cc] +
                        s_part[3][row][cc] + b3[cc];
        const int r = r0 + row;
        const int bb = r & 255;   // batch index
        const int tt2 = r >> 8;   // time index
        out[((size_t)bb * 256 + tt2) * 16 + cc] = v;
    }
}

// =====================================================================
extern "C" void kernel_launch(void* const* d_in, const int* in_sizes, int n_in,
                              void* d_out, int out_size, void* d_ws, size_t ws_size,
                              hipStream_t stream) {
    (void)in_sizes; (void)n_in; (void)out_size; (void)ws_size;
    const float* ts      = (const float*)d_in[0];
    const float* yi      = (const float*)d_in[1];
    const float* gru_wih = (const float*)d_in[2];
    const float* gru_whh = (const float*)d_in[3];
    const float* gru_b   = (const float*)d_in[4];
    const float* gru_bn  = (const float*)d_in[5];
    const float* h2o_W1  = (const float*)d_in[6];
    const float* h2o_b1  = (const float*)d_in[7];
    const float* h2o_W2  = (const float*)d_in[8];
    const float* h2o_b2  = (const float*)d_in[9];
    const float* h2o_W3  = (const float*)d_in[10];
    const float* h2o_b3  = (const float*)d_in[11];
    const float* cf_W0   = (const float*)d_in[12];
    const float* cf_W1   = (const float*)d_in[13];
    const float* cf_W2   = (const float*)d_in[14];
    const float* cf_Wout = (const float*)d_in[15];
    const float* o2d_W1  = (const float*)d_in[16];
    const float* o2d_b1  = (const float*)d_in[17];
    const float* o2d_W2  = (const float*)d_in[18];
    const float* o2d_b2  = (const float*)d_in[19];
    const float* o2d_W3  = (const float*)d_in[20];
    const float* o2d_b3  = (const float*)d_in[21];

    u32* ys = (u32*)d_ws;  // [256,256,32] packed f16 (hi | lo<<16) = 4 MB

    gru_h2o_kernel<<<256, 512, 0, stream>>>(yi, gru_wih, gru_whh, gru_b, gru_bn,
                                            h2o_W1, h2o_b1, h2o_W2, h2o_b2, h2o_W3, h2o_b3, ys);
    ode_kernel<<<256, 512, 0, stream>>>(ts, cf_W0, cf_W1, cf_W2, cf_Wout, ys);
    o2d_kernel<<<4096, 256, 0, stream>>>(ys, o2d_W1, o2d_b1, o2d_W2, o2d_b2,
                                         o2d_W3, o2d_b3, (float*)d_out);
}